// Round 1
// baseline (169.994 us; speedup 1.0000x reference)
//
#include <hip/hip_runtime.h>

// SRL embeddings, fused single kernel — R3: tail-smoothing + parallel Phase B.
// Shapes fixed: B=16,S=16,L=128,D=768,A=8,T=5.
//
// R2 analysis: kernel ~37us vs ~16us BW floor. Three causes attacked here:
//  (1) grid was exactly-resident (6 blk/CU) -> no dynamic rebalancing of the
//      len-dependent per-block work. Now CHUNK=16 -> 3072 blocks, 8 resident
//      per CU (wave-cap), 12 avg -> 4/CU scheduled dynamically = tail smoothing.
//  (2) Phase B was a serial 128x5 scan on 24 divergent lanes of wave 0
//      (~1.2us wave-serial per block, barrier-exposed). Now: ballot-count on
//      2 full waves + parallel list build on 128 threads with LDS atomics.
//  (3) Phase C streamed 49KB through 32KB L1 -> Phase D re-reads missed L1.
//      Now a block streams 24.6KB -> Phase D re-reads are L1 hits.

namespace {
constexpr int Bc = 16, Sc = 16, Lc = 128, Dc = 768, Ac = 8, Tc = 5;
constexpr int NF4    = Dc / 4;          // 192 float4 per row
constexpr int CHUNK  = 16;              // float4 columns per block (256B slice)
constexpr int NCHUNK = NF4 / CHUNK;     // 12
constexpr int BLOCK  = 256;             // 4 waves
constexpr int RP     = BLOCK / CHUNK;   // 16 l-phases
constexpr int NSLOT  = 3 * Ac;          // 24 arg slots
constexpr int NTOK   = NSLOT * Tc;      // 120 staged tokens
constexpr int OUT1   = Bc * Sc * NF4;       // sentence output, float4 units
constexpr int OUTG   = Bc * Sc * Ac * NF4;  // per-arg-type output, float4 units
}

__global__ __launch_bounds__(BLOCK) void srl_fused(
    const float4* __restrict__ hid,
    const int*    __restrict__ sids,
    const int*    __restrict__ amask,
    const int*    __restrict__ pids,
    const int*    __restrict__ a0ids,
    const int*    __restrict__ a1ids,
    float4*       __restrict__ out)
{
  const int c   = blockIdx.x;           // column chunk 0..11
  const int bs  = blockIdx.y;           // (b,s) 0..255
  const int tid = threadIdx.x;
  const int q   = tid & (CHUNK - 1);    // float4 column within chunk
  const int r   = tid >> 4;             // l-phase 0..15

  __shared__ int     sid[Lc];
  __shared__ int     tok_s[NTOK];       // all 24 slots x 5 tokens
  __shared__ int     cnt_s[NTOK];       // match counts per token
  __shared__ int     sel_s[NSLOT];      // selected token per slot (-1 = none)
  __shared__ int     scnt_s[NSLOT];     // match count of selected token
  __shared__ int     lpos_s[NSLOT];     // append cursor for slist
  __shared__ unsigned char slist[NSLOT][Lc];
  __shared__ float4  red[BLOCK];

  // ---- Phase A: stage sentence ids + all arg tokens; len via sync_count. ----
  int mval = 0;
  if (tid < Lc) {
    sid[tid] = sids[bs * Lc + tid];
    mval     = amask[bs * Lc + tid];
  } else if (tid < Lc + NTOK) {
    const int k   = tid - Lc;           // 0..119 = (g*8 + a)*5 + t
    const int g   = k / (Ac * Tc);
    const int rem = k - g * (Ac * Tc);
    const int* ids = (g == 0 ? pids : (g == 1 ? a0ids : a1ids));
    tok_s[k] = ids[bs * Ac * Tc + rem];
    cnt_s[k] = 0;
  }
  const int len = __syncthreads_count(mval != 0);   // prefix mask -> length

  const float4* __restrict__ hrow = hid + (size_t)bs * Lc * NF4 + c * CHUNK;

  // ---- Phase C: pooling partial sums over the valid prefix (loads first). ----
  float ax = 0.f, ay = 0.f, az = 0.f, aw = 0.f;
#pragma unroll 4
  for (int l = r; l < len; l += RP) {
    const float4 v = hrow[l * NF4 + q];
    ax += v.x; ay += v.y; az += v.z; aw += v.w;
  }
  red[tid] = make_float4(ax, ay, az, aw);

  // ---- Phase B1: ballot-count all 120 tokens on 2 full waves (tid<128). ----
  if (tid < Lc) {
    const int  v     = sid[tid];
    const bool lane0 = ((tid & 63) == 0);
    for (int k = 0; k < NTOK; ++k) {
      const unsigned long long m = __ballot(v == tok_s[k]);
      if (lane0 && m) atomicAdd(&cnt_s[k], __popcll(m));
    }
  }
  __syncthreads();   // red + cnt ready

  // ---- Phase C2 (wave 0): reduce 16 l-phases, write sentence embedding. ----
  if (tid < CHUNK) {
    float4 s = red[tid];
#pragma unroll
    for (int p = 1; p < RP; ++p) {
      const float4 t = red[p * CHUNK + tid];
      s.x += t.x; s.y += t.y; s.z += t.z; s.w += t.w;
    }
    const float inv = 1.0f / (float)(len > 0 ? len : 1);
    s.x *= inv; s.y *= inv; s.z *= inv; s.w *= inv;
    out[bs * NF4 + c * CHUNK + tid] = s;
  }
  // ---- Phase B2 (wave 1, parallel with C2): pick LAST valid token/slot. ----
  else if (tid >= 64 && tid < 64 + NSLOT) {
    const int j = tid - 64;
    int selv = -1, n = 0;
#pragma unroll
    for (int t = Tc - 1; t >= 0; --t) {
      const int tokv = tok_s[j * Tc + t];
      const int cv   = cnt_s[j * Tc + t];
      if (n == 0 && tokv != 0 && cv > 0) { selv = tokv; n = cv; }
    }
    sel_s[j]  = selv;
    scnt_s[j] = n;
    lpos_s[j] = 0;
  }
  __syncthreads();   // sel/scnt/lpos ready

  // ---- Phase B3: build match lists, 128 threads, order-irrelevant. ----
  if (tid < Lc) {
    const int v = sid[tid];
#pragma unroll
    for (int j = 0; j < NSLOT; ++j) {
      if (v == sel_s[j]) {
        const int p = atomicAdd(&lpos_s[j], 1);
        slist[j][p] = (unsigned char)tid;
      }
    }
  }
  __syncthreads();   // slists ready

  // ---- Phase D: arg embeddings; match rows are L1-hot (24.6KB < 32KB L1). ----
  for (int j = r; j < NSLOT; j += RP) {
    const int n = scnt_s[j];
    float ox = 0.f, oy = 0.f, oz = 0.f, ow = 0.f;
    if (n > 0) {
      for (int i = 0; i < n; ++i) {
        const int l = (int)slist[j][i];   // broadcast read
        const float4 v = hrow[l * NF4 + q];
        ox += v.x; oy += v.y; oz += v.z; ow += v.w;
      }
      const float inv = 1.0f / (float)n;
      ox *= inv; oy *= inv; oz *= inv; ow *= inv;
    }
    const int g = j / Ac, a = j - g * Ac;
    out[OUT1 + g * OUTG + (bs * Ac + a) * NF4 + c * CHUNK + q] =
        make_float4(ox, oy, oz, ow);
  }
}

extern "C" void kernel_launch(void* const* d_in, const int* in_sizes, int n_in,
                              void* d_out, int out_size, void* d_ws, size_t ws_size,
                              hipStream_t stream) {
  const float4* hid   = (const float4*)d_in[0];
  const int*    sids  = (const int*)d_in[1];
  const int*    amask = (const int*)d_in[2];
  const int*    pids  = (const int*)d_in[3];
  const int*    a0ids = (const int*)d_in[4];
  const int*    a1ids = (const int*)d_in[5];
  float4*       out   = (float4*)d_out;

  srl_fused<<<dim3(NCHUNK, Bc * Sc), dim3(BLOCK), 0, stream>>>(
      hid, sids, amask, pids, a0ids, a1ids, out);
}

// Round 2
// 166.761 us; speedup vs baseline: 1.0194x; 1.0194x over previous
//
#include <hip/hip_runtime.h>

// SRL embeddings, fused single kernel — R4: R2 structure + 8-wave blocks.
// Shapes fixed: B=16,S=16,L=128,D=768,A=8,T=5.
//
// R3 post-mortem: ballot-based Phase B cost ~12us (3.7x the scan work of R2's
// serial form, un-overlapped); reverted to R2's Phase B (24 lanes of wave 0,
// overlapped with pooling on the other waves).
// R4 change: BLOCK 256->512 (8 waves), CHUNK stays 32 (512B slices, 1536
// blocks). Resident = 4 blocks/CU = 32 waves (max occupancy, was 24); grid
// offers 6/CU -> ~2/CU dynamically scheduled -> smooths the len-dependent
// per-CU tail (sum of 6 uniform(64,128) lens, max over 256 CUs ~ +20%).

namespace {
constexpr int Bc = 16, Sc = 16, Lc = 128, Dc = 768, Ac = 8, Tc = 5;
constexpr int NF4    = Dc / 4;          // 192 float4 per row
constexpr int CHUNK  = 32;              // float4 columns per block (512B slice)
constexpr int NCHUNK = NF4 / CHUNK;     // 6
constexpr int BLOCK  = 512;             // 8 waves
constexpr int RP     = BLOCK / CHUNK;   // 16 l-phases
constexpr int NSLOT  = 3 * Ac;          // 24 arg slots
constexpr int OUT1   = Bc * Sc * NF4;       // sentence output, float4 units
constexpr int OUTG   = Bc * Sc * Ac * NF4;  // per-arg-type output, float4 units
}

__global__ __launch_bounds__(BLOCK) void srl_fused(
    const float4* __restrict__ hid,
    const int*    __restrict__ sids,
    const int*    __restrict__ amask,
    const int*    __restrict__ pids,
    const int*    __restrict__ a0ids,
    const int*    __restrict__ a1ids,
    float4*       __restrict__ out)
{
  const int c   = blockIdx.x;           // column chunk 0..5
  const int bs  = blockIdx.y;           // (b,s) 0..255
  const int tid = threadIdx.x;
  const int q   = tid & (CHUNK - 1);    // float4 column within chunk
  const int r   = tid >> 5;             // l-phase 0..15

  __shared__ int    sid[Lc];
  __shared__ short  slist[NSLOT][Lc];
  __shared__ int    scnt[NSLOT];
  __shared__ float4 red[BLOCK];

  // Phase A: stage sentence ids; prefix length via __syncthreads_count.
  int mval = 0;
  if (tid < Lc) {
    sid[tid] = sids[bs * Lc + tid];
    mval     = amask[bs * Lc + tid];
  }
  const int len = __syncthreads_count(mval != 0);

  const float4* __restrict__ hrow = hid + (size_t)bs * Lc * NF4 + c * CHUNK;

  // Phase B (lanes 0..23 of wave 0, overlapped with pooling on waves 1..7):
  // count matches for all 5 tokens in one sid scan, pick LAST valid t
  // (tok!=0 && cnt>0), build its match list.
  if (tid < NSLOT) {
    const int g = tid / Ac, a = tid % Ac;
    const int* ids = (g == 0 ? pids : (g == 1 ? a0ids : a1ids)) + (bs * Ac + a) * Tc;
    int tok[Tc], cnt[Tc];
#pragma unroll
    for (int t = 0; t < Tc; ++t) { tok[t] = ids[t]; cnt[t] = 0; }
    for (int l = 0; l < Lc; ++l) {
      const int v = sid[l];   // broadcast read
#pragma unroll
      for (int t = 0; t < Tc; ++t) cnt[t] += (v == tok[t]) ? 1 : 0;
    }
    int sel = 0, n = 0;
#pragma unroll
    for (int t = Tc - 1; t >= 0; --t) {
      if (n == 0 && tok[t] != 0 && cnt[t] > 0) { sel = tok[t]; n = cnt[t]; }
    }
    scnt[tid] = n;
    if (n > 0) {
      int k = 0;
      for (int l = 0; l < Lc; ++l)
        if (sid[l] == sel) slist[tid][k++] = (short)l;
    }
  }

  // Phase C: pooling partial sums over the valid prefix, l-split by r.
  float ax = 0.f, ay = 0.f, az = 0.f, aw = 0.f;
#pragma unroll 4
  for (int l = r; l < len; l += RP) {
    const float4 v = hrow[l * NF4 + q];
    ax += v.x; ay += v.y; az += v.z; aw += v.w;
  }
  red[tid] = make_float4(ax, ay, az, aw);
  __syncthreads();   // red ready; also publishes scnt/slist for Phase D

  // Phase C2: reduce the 16 l-phases, divide by len, write sentence embedding.
  if (tid < CHUNK) {
    float4 s = red[q];
#pragma unroll
    for (int p = 1; p < RP; ++p) {
      const float4 t = red[p * CHUNK + q];
      s.x += t.x; s.y += t.y; s.z += t.z; s.w += t.w;
    }
    const float inv = 1.0f / (float)(len > 0 ? len : 1);
    s.x *= inv; s.y *= inv; s.z *= inv; s.w *= inv;
    out[bs * NF4 + c * CHUNK + q] = s;
  }

  // Phase D: arg embeddings. r=0..7 handle two slots {r, r+16}, r=8..15 one.
  for (int j = r; j < NSLOT; j += RP) {
    const int n = scnt[j];
    float ox = 0.f, oy = 0.f, oz = 0.f, ow = 0.f;
    if (n > 0) {
      for (int i = 0; i < n; ++i) {
        const int l = (int)slist[j][i];   // broadcast read
        const float4 v = hrow[l * NF4 + q];
        ox += v.x; oy += v.y; oz += v.z; ow += v.w;
      }
      const float inv = 1.0f / (float)n;
      ox *= inv; oy *= inv; oz *= inv; ow *= inv;
    }
    const int g = j / Ac, a = j - g * Ac;
    out[OUT1 + g * OUTG + (bs * Ac + a) * NF4 + c * CHUNK + q] =
        make_float4(ox, oy, oz, ow);
  }
}

extern "C" void kernel_launch(void* const* d_in, const int* in_sizes, int n_in,
                              void* d_out, int out_size, void* d_ws, size_t ws_size,
                              hipStream_t stream) {
  const float4* hid   = (const float4*)d_in[0];
  const int*    sids  = (const int*)d_in[1];
  const int*    amask = (const int*)d_in[2];
  const int*    pids  = (const int*)d_in[3];
  const int*    a0ids = (const int*)d_in[4];
  const int*    a1ids = (const int*)d_in[5];
  float4*       out   = (float4*)d_out;

  srl_fused<<<dim3(NCHUNK, Bc * Sc), dim3(BLOCK), 0, stream>>>(
      hid, sids, amask, pids, a0ids, a1ids, out);
}